// Round 3
// baseline (104.689 us; speedup 1.0000x reference)
//
#include <hip/hip_runtime.h>

// Problem: A=1, B=32, M=32, H=1024, E=8, N=1024 (all fp32)
// out[b,e] = mask[b,e] * sum_h (sum_m hidden[b,m,h]) * (sum_n weight[e,h,n])
//
// Single-node design: R2's verified reduce body + last-64-blocks dot, joined by
// a device-scope arrival counter in ws. No second kernel node, no memset node,
// no redundant global traffic, no contended output atomics.
//
// Counter init problem: ws is re-poisoned by the harness each iteration with a
// single uniform-pattern 256 MiB fill. So a never-written guard word in ws
// equals the counter word's pre-kernel value. rank = (old - guard) & 511 is
// robust both to per-iteration re-poison (counter resets to guard) and to
// no-repoison (counter advances exactly 512 per run).
//
// ws word-layout: wsum [0,8192) | hsum [8192,40960) | cnt u32 @ 40960 |
//                 guard u32 @ 40992 (separate 128B line, never written)

#define Bdim 32
#define Mdim 32
#define Hdim 1024
#define Edim 8
#define Ndim 1024

#define CNT_W   40960
#define GUARD_W 40992

__global__ __launch_bounds__(256) void fused1(
    const float* __restrict__ hidden,    // (B,M,H)
    const float* __restrict__ weight,    // (E,H,N)
    const float* __restrict__ sparsity,  // (B,E) flat
    float* __restrict__ out,             // (B,E) flat
    float* __restrict__ ws)
{
    const int wave = threadIdx.x >> 6;
    const int lane = threadIdx.x & 63;
    unsigned int* const cnt = reinterpret_cast<unsigned int*>(ws) + CNT_W;
    const unsigned int g = reinterpret_cast<const unsigned int*>(ws)[GUARD_W];

    // ---- Phase A: weight row sums. Block owns rows [blockIdx*16, +16),
    //      wave w owns 4. 64 KB/block, coalesced float4. (R2-verified)
    {
        const float4* w4 = reinterpret_cast<const float4*>(weight);
        #pragma unroll
        for (int r = 0; r < 4; ++r) {
            const int row = blockIdx.x * 16 + wave * 4 + r;   // row = e*H + h
            float s = 0.f;
            #pragma unroll
            for (int j = 0; j < 4; ++j) {
                float4 v = w4[row * (Ndim / 4) + j * 64 + lane];
                s += (v.x + v.y) + (v.z + v.w);
            }
            #pragma unroll
            for (int off = 32; off > 0; off >>= 1)
                s += __shfl_xor(s, off, 64);
            if (lane == 0) ws[row] = s;
        }
    }

    // ---- Phase B: hidden M-sums, 16 float4-columns per block, wave 0 only,
    //      4 lanes per column + 2 shfl_xor combine. (R2-verified)
    if (threadIdx.x < 64) {
        const int c  = blockIdx.x * 16 + (lane & 15);   // 0..8191
        const int mg = lane >> 4;                        // 0..3
        const int b  = c >> 8;
        const int h4 = c & 255;
        const float4* hp = reinterpret_cast<const float4*>(hidden)
                         + b * (Mdim * Hdim / 4) + h4;
        float4 s = {0.f, 0.f, 0.f, 0.f};
        #pragma unroll
        for (int m = 0; m < 8; ++m) {
            float4 v = hp[(mg * 8 + m) * (Hdim / 4)];
            s.x += v.x; s.y += v.y; s.z += v.z; s.w += v.w;
        }
        #pragma unroll
        for (int off = 16; off <= 32; off <<= 1) {
            s.x += __shfl_xor(s.x, off, 64);
            s.y += __shfl_xor(s.y, off, 64);
            s.z += __shfl_xor(s.z, off, 64);
            s.w += __shfl_xor(s.w, off, 64);
        }
        if (mg == 0)
            reinterpret_cast<float4*>(ws + Edim * Hdim)[c] = s;
    }

    // ---- Arrival protocol. __syncthreads() drains this block's stores
    //      (s_waitcnt vmcnt(0) precedes s_barrier), then release-fence + add.
    __shared__ unsigned int rel_s;
    __syncthreads();
    if (threadIdx.x == 0) {
        __threadfence();                       // release (agent scope)
        rel_s = atomicAdd(cnt, 1u) - g;        // = 512*k + rank
    }
    __syncthreads();
    const unsigned int rel  = rel_s;
    const unsigned int rank = rel & 511u;
    if (rank < 448u) return;                   // not among last 64 arrivals

    // ---- Wait for all 512 arrivals of this run (agent-scope acquire loads,
    //      bypass L1 so the spin can't read a stale line).
    if (threadIdx.x == 0) {
        const unsigned int target = (rel & ~511u) + 512u;
        while (__hip_atomic_load(cnt, __ATOMIC_ACQUIRE,
                                 __HIP_MEMORY_SCOPE_AGENT) - g < target) {
            __builtin_amdgcn_s_sleep(8);
        }
    }
    __syncthreads();
    __threadfence();                           // acquire: invalidate stale L1

    // ---- Dot: block rank' in [0,64), 4 outputs (one per wave). Same body as
    //      the old dot_kernel. Reads are L2/L3-resident (160 KB total).
    const int o = (int)(rank - 448u) * 4 + wave;   // b*E + e, 0..255
    const int b = o >> 3;
    const int e = o & 7;
    const float4* hs = reinterpret_cast<const float4*>(ws + Edim * Hdim + b * Hdim);
    const float4* wv = reinterpret_cast<const float4*>(ws + e * Hdim);
    float s = 0.f;
    #pragma unroll
    for (int j = 0; j < 4; ++j) {
        float4 h4 = hs[j * 64 + lane];
        float4 w4 = wv[j * 64 + lane];
        s += h4.x * w4.x + h4.y * w4.y + h4.z * w4.z + h4.w * w4.w;
    }
    #pragma unroll
    for (int off = 32; off > 0; off >>= 1)
        s += __shfl_xor(s, off, 64);
    if (lane == 0) out[o] = s * sparsity[o];
}

extern "C" void kernel_launch(void* const* d_in, const int* in_sizes, int n_in,
                              void* d_out, int out_size, void* d_ws, size_t ws_size,
                              hipStream_t stream) {
    const float* hidden   = (const float*)d_in[0];  // (1,32,32,1024)
    const float* sparsity = (const float*)d_in[1];  // (1,32,1,8)
    const float* weight   = (const float*)d_in[2];  // (1,8,1024,1024)
    float* out = (float*)d_out;                     // (1,32,8)
    float* ws  = (float*)d_ws;

    fused1<<<512, 256, 0, stream>>>(hidden, weight, sparsity, out, ws);
}

// Round 4
// 85.913 us; speedup vs baseline: 1.2185x; 1.2185x over previous
//
#include <hip/hip_runtime.h>

// Problem: A=1, B=32, M=32, H=1024, E=8, N=1024 (all fp32)
// out[b,e] = mask[b,e] * sum_h (sum_m hidden[b,m,h]) * (sum_n weight[e,h,n])
//
// Single-node design, round 2 of the sync protocol:
//  R3 failed because agent-scope ACQUIRE per spin iteration = buffer_inv sc1
//  (full L1+L2 invalidate) per poll, and __threadfence() release = buffer_wbl2
//  per block. This version:
//   - producers publish wsum/hsum via agent-scope RELAXED atomic stores
//     (write-through past the non-coherent per-XCD L2 -- coherent by the HIP
//     memory model with no fence, no cache walk)
//   - arrival: s_waitcnt vmcnt(0) then RELAXED fetch_add (stores visible first)
//   - spin: RELAXED agent loads (coherence-point reads, no cache maintenance),
//     then ONE acquire load (one buffer_inv per reader block, 64 total)
//
// Guard/rank protocol (R3-verified correct): ws is re-poisoned with a uniform
// pattern, so a never-written guard word equals cnt's pre-kernel value;
// rank = (old - guard) & 511 is robust to repoison and no-repoison.
//
// ws word-layout: wsum [0,8192) | hsum [8192,40960) | cnt u32 @ 40960 |
//                 guard u32 @ 40992 (separate line, never written)

#define Bdim 32
#define Mdim 32
#define Hdim 1024
#define Edim 8
#define Ndim 1024

#define CNT_W   40960
#define GUARD_W 40992

__device__ __forceinline__ void store_agent(float* p, float v) {
    __hip_atomic_store(p, v, __ATOMIC_RELAXED, __HIP_MEMORY_SCOPE_AGENT);
}

__global__ __launch_bounds__(256) void fused1(
    const float* __restrict__ hidden,    // (B,M,H)
    const float* __restrict__ weight,    // (E,H,N)
    const float* __restrict__ sparsity,  // (B,E) flat
    float* __restrict__ out,             // (B,E) flat
    float* __restrict__ ws)
{
    const int wave = threadIdx.x >> 6;
    const int lane = threadIdx.x & 63;
    unsigned int* const cnt = reinterpret_cast<unsigned int*>(ws) + CNT_W;
    const unsigned int g = reinterpret_cast<const unsigned int*>(ws)[GUARD_W];

    // ---- Phase A: weight row sums. Block owns rows [blockIdx*16, +16),
    //      wave w owns 4. 64 KB/block, coalesced float4. (R2-verified)
    {
        const float4* w4 = reinterpret_cast<const float4*>(weight);
        #pragma unroll
        for (int r = 0; r < 4; ++r) {
            const int row = blockIdx.x * 16 + wave * 4 + r;   // row = e*H + h
            float s = 0.f;
            #pragma unroll
            for (int j = 0; j < 4; ++j) {
                float4 v = w4[row * (Ndim / 4) + j * 64 + lane];
                s += (v.x + v.y) + (v.z + v.w);
            }
            #pragma unroll
            for (int off = 32; off > 0; off >>= 1)
                s += __shfl_xor(s, off, 64);
            if (lane == 0) store_agent(ws + row, s);
        }
    }

    // ---- Phase B: hidden M-sums, 16 float4-columns per block, wave 0 only,
    //      4 lanes per column + 2 shfl_xor combine. (R2-verified)
    if (threadIdx.x < 64) {
        const int c  = blockIdx.x * 16 + (lane & 15);   // 0..8191
        const int mg = lane >> 4;                        // 0..3
        const int b  = c >> 8;
        const int h4 = c & 255;
        const float4* hp = reinterpret_cast<const float4*>(hidden)
                         + b * (Mdim * Hdim / 4) + h4;
        float4 s = {0.f, 0.f, 0.f, 0.f};
        #pragma unroll
        for (int m = 0; m < 8; ++m) {
            float4 v = hp[(mg * 8 + m) * (Hdim / 4)];
            s.x += v.x; s.y += v.y; s.z += v.z; s.w += v.w;
        }
        #pragma unroll
        for (int off = 16; off <= 32; off <<= 1) {
            s.x += __shfl_xor(s.x, off, 64);
            s.y += __shfl_xor(s.y, off, 64);
            s.z += __shfl_xor(s.z, off, 64);
            s.w += __shfl_xor(s.w, off, 64);
        }
        if (mg == 0) {
            float* d = ws + Edim * Hdim + c * 4;
            store_agent(d + 0, s.x);
            store_agent(d + 1, s.y);
            store_agent(d + 2, s.z);
            store_agent(d + 3, s.w);
        }
    }

    // ---- Arrival: all sc1 stores complete (vmcnt 0), then relaxed tick.
    __shared__ unsigned int rel_s;
    __syncthreads();
    if (threadIdx.x == 0) {
        asm volatile("s_waitcnt vmcnt(0)" ::: "memory");
        rel_s = __hip_atomic_fetch_add(cnt, 1u, __ATOMIC_RELAXED,
                                       __HIP_MEMORY_SCOPE_AGENT) - g;
    }
    __syncthreads();
    const unsigned int rel  = rel_s;
    const unsigned int rank = rel & 511u;
    if (rank < 448u) return;                   // not among last 64 arrivals

    // ---- Wait: relaxed polls (no cache maintenance), one acquire at exit.
    if (threadIdx.x == 0) {
        const unsigned int target = (rel & ~511u) + 512u;
        while (__hip_atomic_load(cnt, __ATOMIC_RELAXED,
                                 __HIP_MEMORY_SCOPE_AGENT) - g < target) {
            __builtin_amdgcn_s_sleep(2);
        }
        // single acquire: one buffer_inv so post-spin plain loads are fresh
        (void)__hip_atomic_load(cnt, __ATOMIC_ACQUIRE,
                                __HIP_MEMORY_SCOPE_AGENT);
    }
    __syncthreads();

    // ---- Dot: reader block rank' in [0,64), 4 outputs (one per wave).
    const int o = (int)(rank - 448u) * 4 + wave;   // b*E + e, 0..255
    const int b = o >> 3;
    const int e = o & 7;
    const float4* hs = reinterpret_cast<const float4*>(ws + Edim * Hdim + b * Hdim);
    const float4* wv = reinterpret_cast<const float4*>(ws + e * Hdim);
    float s = 0.f;
    #pragma unroll
    for (int j = 0; j < 4; ++j) {
        float4 h4 = hs[j * 64 + lane];
        float4 w4 = wv[j * 64 + lane];
        s += h4.x * w4.x + h4.y * w4.y + h4.z * w4.z + h4.w * w4.w;
    }
    #pragma unroll
    for (int off = 32; off > 0; off >>= 1)
        s += __shfl_xor(s, off, 64);
    if (lane == 0) out[o] = s * sparsity[o];
}

extern "C" void kernel_launch(void* const* d_in, const int* in_sizes, int n_in,
                              void* d_out, int out_size, void* d_ws, size_t ws_size,
                              hipStream_t stream) {
    const float* hidden   = (const float*)d_in[0];  // (1,32,32,1024)
    const float* sparsity = (const float*)d_in[1];  // (1,32,1,8)
    const float* weight   = (const float*)d_in[2];  // (1,8,1024,1024)
    float* out = (float*)d_out;                     // (1,32,8)
    float* ws  = (float*)d_ws;

    fused1<<<512, 256, 0, stream>>>(hidden, weight, sparsity, out, ws);
}

// Round 5
// 79.272 us; speedup vs baseline: 1.3206x; 1.0838x over previous
//
#include <hip/hip_runtime.h>

// Problem: A=1, B=32, M=32, H=1024, E=8, N=1024 (all fp32)
// out[b,e] = mask[b,e] * sum_h (sum_m hidden[b,m,h]) * (sum_n weight[e,h,n])
//
// REVERT to the round-0 two-kernel structure -- the best-measured variant
// (79.5 us). Session A/B evidence:
//   R0 two-kernel 640+64 blocks:              79.5 us   <- this kernel
//   R2 two-kernel 512+64 rebalanced:          80.6 us   (noise-equal)
//   R1 fused, out-atomics:                    93.3 us   (atomic funnel)
//   R3 fused, counter + acquire-spin:        104.7 us   (buffer_inv storm)
//   R4 fused, counter + relaxed protocol:     85.9 us   (write-through tail)
// Conclusion: the inter-kernel boundary is NOT a cost; single-node designs
// pay more in coherence-protocol overhead than they save in launch gap.
// Remaining timed window is dominated by harness reset traffic (256 MiB
// poison fill @ ~6.2 TB/s + small memsets), which kernel_launch cannot touch.
//
// ws layout (floats): [0, E*H)          wsum  (8192)
//                     [E*H, E*H + B*H)  hsum  (32768)

#define Bdim 32
#define Mdim 32
#define Hdim 1024
#define Edim 8
#define Ndim 1024

// Kernel A: both streaming reductions in one launch.
// blocks [0,512): weight rows (2048 waves x 4 rows, one wave per row of N=1024)
// blocks [512,640): hidden M-reduction, thread per (b,h), coalesced over h
__global__ __launch_bounds__(256) void reduce_kernel(
    const float* __restrict__ hidden,   // (B,M,H)
    const float* __restrict__ weight,   // (E,H,N)
    float* __restrict__ ws)
{
    constexpr int NB_W = 512;
    if (blockIdx.x < NB_W) {
        const int wave = blockIdx.x * 4 + (threadIdx.x >> 6);
        const int lane = threadIdx.x & 63;
        const float4* w4 = reinterpret_cast<const float4*>(weight);
        #pragma unroll
        for (int r = 0; r < 4; ++r) {
            const int row = wave * 4 + r;          // row = e*H + h, 0..8191
            float s = 0.f;
            #pragma unroll
            for (int j = 0; j < 4; ++j) {
                float4 v = w4[row * (Ndim / 4) + j * 64 + lane];
                s += (v.x + v.y) + (v.z + v.w);
            }
            #pragma unroll
            for (int off = 32; off > 0; off >>= 1)
                s += __shfl_xor(s, off, 64);
            if (lane == 0) ws[row] = s;
        }
    } else {
        const int idx = (blockIdx.x - NB_W) * 256 + threadIdx.x;  // b*H + h
        const int b = idx >> 10;
        const int h = idx & 1023;
        const float* p = hidden + b * (Mdim * Hdim) + h;
        float s = 0.f;
        #pragma unroll
        for (int m = 0; m < Mdim; ++m) s += p[m * Hdim];
        ws[Edim * Hdim + idx] = s;
    }
}

// Kernel B: 256 waves, one per (b,e); dot over h=1024 of hsum[b,:]*wsum[e,:],
// masked by sparsity[b,e].
__global__ __launch_bounds__(256) void dot_kernel(
    const float* __restrict__ ws,
    const float* __restrict__ sparsity,  // (B,E) flat
    float* __restrict__ out)             // (B,E) flat
{
    const int o = blockIdx.x * 4 + (threadIdx.x >> 6);   // b*E + e, 0..255
    const int lane = threadIdx.x & 63;
    const int b = o >> 3;
    const int e = o & 7;
    const float* hsum = ws + Edim * Hdim + b * Hdim;
    const float* wsum = ws + e * Hdim;
    float s = 0.f;
    #pragma unroll
    for (int j = 0; j < 16; ++j) {
        const int h = j * 64 + lane;
        s += hsum[h] * wsum[h];
    }
    #pragma unroll
    for (int off = 32; off > 0; off >>= 1)
        s += __shfl_xor(s, off, 64);
    if (lane == 0) out[o] = s * sparsity[o];
}

extern "C" void kernel_launch(void* const* d_in, const int* in_sizes, int n_in,
                              void* d_out, int out_size, void* d_ws, size_t ws_size,
                              hipStream_t stream) {
    const float* hidden   = (const float*)d_in[0];  // (1,32,32,1024)
    const float* sparsity = (const float*)d_in[1];  // (1,32,1,8)
    const float* weight   = (const float*)d_in[2];  // (1,8,1024,1024)
    float* out = (float*)d_out;                     // (1,32,8)
    float* ws  = (float*)d_ws;

    reduce_kernel<<<640, 256, 0, stream>>>(hidden, weight, ws);
    dot_kernel<<<64, 256, 0, stream>>>(ws, sparsity, out);
}